// Round 5
// baseline (1833.898 us; speedup 1.0000x reference)
//
#include <hip/hip_runtime.h>

#define D_DIM 256
#define K_CODES 1024

// async global->LDS, 16B per lane; LDS dest = wave-uniform base + lane*16
__device__ __forceinline__ void gload16(const float* g, float4* l) {
    __builtin_amdgcn_global_load_lds(
        (const __attribute__((address_space(1))) void*)g,
        (__attribute__((address_space(3))) void*)l, 16, 0, 0);
}

// ---------------------------------------------------------------------------
// Fused prep: blocks [0,128) z2 | [128,132) e2 | [132,388) ET transpose |
//             [388,420) rowKey init (+lossAcc zero)
// NUMERICS: e2 chain (float4 x,y,z,w ascending) must stay bit-identical —
// it discriminates codes. z2 kept as the validated ascending-d chain.
// ---------------------------------------------------------------------------
__global__ __launch_bounds__(256) void k_prep(const float* __restrict__ z,
                                              const float* __restrict__ e,
                                              float* __restrict__ z2,
                                              float* __restrict__ e2,
                                              float* __restrict__ et,
                                              unsigned long long* __restrict__ rowKey,
                                              float* __restrict__ lossAcc) {
    __shared__ float tile[32][33];
    const int bi = blockIdx.x;
    const int t  = threadIdx.x;
    if (bi < 128) {                    // ---- z2 ----
        int n = bi * 256 + t;
        int b = n >> 10, nl = n & 1023;
        const float* p = z + (size_t)b * (D_DIM * 1024) + nl;
        float s = 0.f;
#pragma unroll 8
        for (int d = 0; d < D_DIM; ++d) {
            float v = p[(size_t)d * 1024];
            s = fmaf(v, v, s);
        }
        z2[n] = s;
    } else if (bi < 132) {             // ---- e2 ----
        int k = (bi - 128) * 256 + t;
        const float4* p = (const float4*)(e + (size_t)k * D_DIM);
        float s = 0.f;
#pragma unroll 4
        for (int c = 0; c < D_DIM / 4; ++c) {
            float4 v = p[c];
            s = fmaf(v.x, v.x, s); s = fmaf(v.y, v.y, s);
            s = fmaf(v.z, v.z, s); s = fmaf(v.w, v.w, s);
        }
        e2[k] = s;
    } else if (bi < 388) {             // ---- ET[d][k] = E[k][d] ----
        int bb = bi - 132;
        const int k0 = (bb & 31) * 32;
        const int d0 = (bb >> 5) * 32;
        {
            int kk = t >> 3, c4 = (t & 7) * 4;
            float4 v = *(const float4*)(e + (size_t)(k0 + kk) * D_DIM + d0 + c4);
            tile[c4 + 0][kk] = v.x; tile[c4 + 1][kk] = v.y;
            tile[c4 + 2][kk] = v.z; tile[c4 + 3][kk] = v.w;
        }
        __syncthreads();
        {
            int dd = t >> 3, kc4 = (t & 7) * 4;
            float4 o;
            o.x = tile[dd][kc4 + 0]; o.y = tile[dd][kc4 + 1];
            o.z = tile[dd][kc4 + 2]; o.w = tile[dd][kc4 + 3];
            *(float4*)(et + (size_t)(d0 + dd) * K_CODES + k0 + kc4) = o;
        }
    } else {                           // ---- rowKey init ----
        int bb = bi - 388;             // 0..31, 1024 u64 each
        if (bb == 0 && t == 0) lossAcc[0] = 0.f;
#pragma unroll
        for (int j = 0; j < 4; ++j)
            rowKey[bb * 1024 + j * 256 + t] = 0xFFFFFFFFFFFFFFFFULL;
    }
}

// ---------------------------------------------------------------------------
// Main: 128 rows x 128 codes per block, K split 8x (grid 2048). Slab = 16 d
// (was 8): 16 barriers instead of 32 — round-4 analysis put ~30% of cycles
// in barrier cadence at 1024 FMA-cycles/slab; now 2048/slab. Double-buffered
// via global_load_lds, s-loop unrolled x2 so all LDS offsets are immediates.
// LDS 32 KB -> 4 blocks/CU -> grid 2048 = exactly 2 resident generations.
// E tile XOR-swizzled on float4 slot (slot c holds element c^(c>>3)): reads
// land 2 per bank-group (free, m136); Z reads are 16-lane broadcasts.
// launch_bounds(256,4): VGPR cap 128 (round 3: (256,8) -> cap 32 -> spill).
// NUMERICS: per (n,k) ze = single ascending-d fp32 FMA chain (d = 0..255 in
// order across slabs), dist = fmaf(-2, ze, fl(z2+e2)) — bit-identical to
// rounds 1/2/4 (validated absmax 0).
// ---------------------------------------------------------------------------
__global__ __launch_bounds__(256, 4) void k_main(const float* __restrict__ z,
                                                 const float* __restrict__ et,
                                                 const float* __restrict__ z2,
                                                 const float* __restrict__ e2,
                                                 unsigned long long* __restrict__ rowKey) {
    __shared__ float4 lds4[2048];   // [buf:2][Z:512 | E:512] float4 = 32 KB

    const int t    = threadIdx.x;
    const int lane = t & 63;
    const int w    = t >> 6;        // wave 0..3
    const int tk   = t & 15;        // code group
    const int tr   = t >> 4;        // row group 0..15
    const int kc   = blockIdx.x & 7;
    const int rb   = blockIdx.x >> 3;
    const int n0   = rb * 128;
    const int b    = n0 >> 10;
    const int nl0  = n0 & 1023;
    const int k0   = kc * 128;

    // staging sources (per-lane). Slab buffer = 512 float4 per matrix:
    // slot (j*256 + w*64 + lane) -> dd = j*8 + w*2 + (lane>>5), c4 = lane&31.
    const int c4   = lane & 31;
    const int sw   = c4 ^ (c4 >> 3);            // involutive float4 swizzle
    const int ddw  = w * 2 + (lane >> 5);       // row within j=0 half
    const float* zsrc = z  + (size_t)b * (D_DIM * 1024) + nl0
                           + (size_t)ddw * 1024 + c4 * 4;
    const float* esrc = et + (size_t)ddw * K_CODES + k0 + sw * 4;

    // reader E slots: element 2tk lives at slot 2tk ^ (tk>>2)
    const int e0 = (2 * tk) ^ (tk >> 2);
    const int e1 = e0 ^ 1;

    // operand prefetch for the distance epilogue (L2-resident, issue early)
    float z2r[8], e2r[8];
#pragma unroll
    for (int i = 0; i < 8; ++i) z2r[i] = z2[n0 + tr * 8 + i];
#pragma unroll
    for (int j = 0; j < 8; ++j) e2r[j] = e2[k0 + tk * 8 + j];

    float acc[8][8];
#pragma unroll
    for (int i = 0; i < 8; ++i)
#pragma unroll
        for (int j = 0; j < 8; ++j) acc[i][j] = 0.f;

#define STAGE(B)                                                         \
    do {                                                                 \
        gload16(zsrc,        &lds4[(B) + w * 64]);                       \
        gload16(zsrc + 8192, &lds4[(B) + 256 + w * 64]);                 \
        gload16(esrc,        &lds4[(B) + 512 + w * 64]);                 \
        gload16(esrc + 8192, &lds4[(B) + 768 + w * 64]);                 \
        zsrc += 16384; esrc += 16384;                                    \
    } while (0)

#define COMPUTE(B)                                                       \
    do {                                                                 \
        const float4* Zr = &lds4[(B) + tr * 2];                          \
        const float4* Er = &lds4[(B) + 512];                             \
        _Pragma("unroll")                                                \
        for (int dd = 0; dd < 16; ++dd) {                                \
            float4 za = Zr[dd * 32];                                     \
            float4 zc = Zr[dd * 32 + 1];                                 \
            float4 ea = Er[dd * 32 + e0];                                \
            float4 eb = Er[dd * 32 + e1];                                \
            float zz[8] = { za.x, za.y, za.z, za.w,                      \
                            zc.x, zc.y, zc.z, zc.w };                    \
            float ee[8] = { ea.x, ea.y, ea.z, ea.w,                      \
                            eb.x, eb.y, eb.z, eb.w };                    \
            _Pragma("unroll")                                            \
            for (int i = 0; i < 8; ++i)                                  \
                _Pragma("unroll")                                        \
                for (int j = 0; j < 8; ++j)                              \
                    acc[i][j] = fmaf(zz[i], ee[j], acc[i][j]);           \
        }                                                                \
    } while (0)

    // prologue: slab 0 -> buf0
    STAGE(0);
    __syncthreads();
    // 16 slabs, unrolled in pairs; constant LDS bases 0 / 1024
    for (int p = 0; p < 8; ++p) {
        STAGE(1024);            // slab 2p+1 -> buf1 (2p+1 <= 15 always)
        COMPUTE(0);             // slab 2p
        __syncthreads();        // drains buf1 loads; buf0 free to overwrite
        if (p < 7) STAGE(0);    // slab 2p+2 -> buf0
        COMPUTE(1024);          // slab 2p+1
        __syncthreads();        // drains buf0 loads; buf1 free
    }
#undef STAGE
#undef COMPUTE

    // dist + within-thread argmin (ascending k => first-min tiebreak)
    unsigned long long bKey[8];
#pragma unroll
    for (int i = 0; i < 8; ++i) bKey[i] = 0xFFFFFFFFFFFFFFFFULL;
#pragma unroll
    for (int i = 0; i < 8; ++i) {
#pragma unroll
        for (int j = 0; j < 8; ++j) {
            float t1 = z2r[i] + e2r[j];              // fl(z2 + e2)
            float dist = fmaf(-2.0f, acc[i][j], t1); // fl(t1 - 2*ze)
            unsigned long long key =
                ((unsigned long long)__float_as_uint(dist) << 32) |
                (unsigned int)(k0 + tk * 8 + j);
            if (key < bKey[i]) bKey[i] = key;
        }
    }
#pragma unroll
    for (int m = 1; m < 16; m <<= 1) {
#pragma unroll
        for (int i = 0; i < 8; ++i) {
            unsigned long long o = __shfl_xor(bKey[i], m, 64);
            if (o < bKey[i]) bKey[i] = o;
        }
    }
    if (tk == 0) {
#pragma unroll
        for (int i = 0; i < 8; ++i)
            atomicMin(&rowKey[n0 + tr * 8 + i], bKey[i]);
    }
}

// ---------------------------------------------------------------------------
// Epilogue: resolve idx from rowKey + z_q gather + straight-through out +
// loss partial sums. 64 rows x 256 d per block.
// ---------------------------------------------------------------------------
__global__ __launch_bounds__(256) void k_epilogue(const float* __restrict__ z,
                                                  const float* __restrict__ e,
                                                  const unsigned long long* __restrict__ rowKey,
                                                  float* __restrict__ outZ,
                                                  float* __restrict__ outIdx,
                                                  float* __restrict__ lossAcc) {
    __shared__ float4 zq4[64][64];
    __shared__ int idxs[64];
    const int t = threadIdx.x;
    const int n0 = blockIdx.x * 64;
    const int b = n0 >> 10, nl0 = n0 & 1023;

    if (t < 64) {
        unsigned long long key = rowKey[n0 + t];
        int bi = (int)(unsigned int)(key & 0xFFFFFFFFULL);
        idxs[t] = bi;
        outIdx[n0 + t] = (float)bi;
    }
    __syncthreads();

#pragma unroll
    for (int j = 0; j < 16; ++j) {
        int flat = j * 256 + t;
        int i  = flat >> 6;
        int c4 = flat & 63;
        float4 v = *(const float4*)(e + (size_t)idxs[i] * D_DIM + c4 * 4);
        zq4[i][c4 ^ (i & 7)] = v;
    }
    __syncthreads();

    const int i  = t & 63;
    const int dg = t >> 6;
    const float* zp = z    + (size_t)b * (D_DIM * 1024) + nl0 + i;
    float*       op = outZ + (size_t)b * (D_DIM * 1024) + nl0 + i;
    float s = 0.f;
#pragma unroll 4
    for (int c = 0; c < 16; ++c) {
        int c4 = dg * 16 + c;
        float4 q = zq4[i][c4 ^ (i & 7)];
        int d = c4 * 4;
        float zv, df;
        zv = zp[(size_t)(d + 0) * 1024]; df = q.x - zv; s = fmaf(df, df, s); op[(size_t)(d + 0) * 1024] = zv + df;
        zv = zp[(size_t)(d + 1) * 1024]; df = q.y - zv; s = fmaf(df, df, s); op[(size_t)(d + 1) * 1024] = zv + df;
        zv = zp[(size_t)(d + 2) * 1024]; df = q.z - zv; s = fmaf(df, df, s); op[(size_t)(d + 2) * 1024] = zv + df;
        zv = zp[(size_t)(d + 3) * 1024]; df = q.w - zv; s = fmaf(df, df, s); op[(size_t)(d + 3) * 1024] = zv + df;
    }
#pragma unroll
    for (int off = 32; off > 0; off >>= 1) s += __shfl_down(s, off, 64);
    if ((t & 63) == 0) atomicAdd(lossAcc, s);
}

__global__ void k_final(const float* __restrict__ lossAcc,
                        float* __restrict__ outLoss) {
    float m = lossAcc[0] * (1.0f / 8388608.0f);
    outLoss[0] = m + 0.25f * m;
}

// ---------------------------------------------------------------------------
extern "C" void kernel_launch(void* const* d_in, const int* in_sizes, int n_in,
                              void* d_out, int out_size, void* d_ws, size_t ws_size,
                              hipStream_t stream) {
    const float* z = (const float*)d_in[0];   // (32,256,32,32)
    const float* e = (const float*)d_in[1];   // (1024,256)
    float* out     = (float*)d_out;
    float* outIdx  = out + 8388608;
    float* outLoss = out + 8421376;

    float* z2      = (float*)d_ws;                         // 32768 f
    float* e2      = z2 + 32768;                           // 1024 f
    float* lossAcc = e2 + 1024;                            // 1 f
    uintptr_t p = (uintptr_t)(lossAcc + 1);
    p = (p + 255) & ~(uintptr_t)255;
    unsigned long long* rowKey = (unsigned long long*)p;   // 32768 u64
    float* et = (float*)(rowKey + 32768);                  // 262144 f

    k_prep<<<420, 256, 0, stream>>>(z, e, z2, e2, et, rowKey, lossAcc);
    k_main<<<2048, 256, 0, stream>>>(z, et, z2, e2, rowKey);
    k_epilogue<<<512, 256, 0, stream>>>(z, e, rowKey, out, outIdx, lossAcc);
    k_final<<<1, 1, 0, stream>>>(lossAcc, outLoss);
}

// Round 6
// 378.855 us; speedup vs baseline: 4.8406x; 4.8406x over previous
//
#include <hip/hip_runtime.h>

#define D_DIM 256
#define K_CODES 1024
#define MARGIN 4e-4f
#define CAP 32

typedef __attribute__((ext_vector_type(8))) short short8;
typedef __attribute__((ext_vector_type(4))) float f32x4;

union Pack8 { unsigned int u[4]; short8 s8; };

// RNE f32 -> bf16 bits (finite inputs only; self-contained, deterministic)
__device__ __forceinline__ unsigned int bfr(float x) {
    unsigned int u = __float_as_uint(x);
    return (u + 0x7FFFu + ((u >> 16) & 1u)) >> 16;
}
__device__ __forceinline__ float bf2f(unsigned int b) {
    return __uint_as_float(b << 16);
}

// ---------------------------------------------------------------------------
// Fused prep: blocks [0,128) z2 | [128,132) e2 | [132,164) e bf16-split.
// NUMERICS: z2/e2 chains bit-identical to the 4x-validated versions.
// ---------------------------------------------------------------------------
__global__ __launch_bounds__(256) void k_prep(const float* __restrict__ z,
                                              const float* __restrict__ e,
                                              float* __restrict__ z2,
                                              float* __restrict__ e2,
                                              unsigned short* __restrict__ ehi,
                                              unsigned short* __restrict__ elo,
                                              float* __restrict__ lossAcc) {
    const int bi = blockIdx.x;
    const int t  = threadIdx.x;
    if (bi < 128) {                    // ---- z2 ----
        int n = bi * 256 + t;
        int b = n >> 10, nl = n & 1023;
        const float* p = z + (size_t)b * (D_DIM * 1024) + nl;
        float s = 0.f;
#pragma unroll 8
        for (int d = 0; d < D_DIM; ++d) {
            float v = p[(size_t)d * 1024];
            s = fmaf(v, v, s);
        }
        z2[n] = s;
    } else if (bi < 132) {             // ---- e2 ----
        int k = (bi - 128) * 256 + t;
        const float4* p = (const float4*)(e + (size_t)k * D_DIM);
        float s = 0.f;
#pragma unroll 4
        for (int c = 0; c < D_DIM / 4; ++c) {
            float4 v = p[c];
            s = fmaf(v.x, v.x, s); s = fmaf(v.y, v.y, s);
            s = fmaf(v.z, v.z, s); s = fmaf(v.w, v.w, s);
        }
        e2[k] = s;
    } else {                           // ---- e split (262144 elems / 32 blk) ----
        if (bi == 132 && t == 0) lossAcc[0] = 0.f;
        int base = (bi - 132) * 8192;
#pragma unroll 8
        for (int j = 0; j < 32; ++j) {
            int idx = base + j * 256 + t;
            float v = e[idx];
            unsigned int hb = bfr(v);
            unsigned int lb = bfr(v - bf2f(hb));
            ehi[idx] = (unsigned short)hb;
            elo[idx] = (unsigned short)lb;
        }
    }
}

// ---------------------------------------------------------------------------
// MFMA shortlist + exact rescore. Block = 4 waves; each wave owns 16 rows x
// all 1024 codes (64 tiles of 16 codes; per tile 8 d-steps x 3 split-MFMAs).
// A-panel (16 rows x 256 d, bf16 hi/lo) built on the fly, held in 64 VGPRs.
// B-frags streamed from ehi/elo (1 MB, L1/L2-resident; block-shared via L1).
// Capture: running per-row min (lane-shared every 2 tiles); k captured when
// score <= m + MARGIN (margin >> 2*total approx error ~1.1e-4 => shortlist
// provably contains the reference coarse argmin). Rescore: exact fp32
// ascending-d FMA chain + fmaf(-2, ze, fl(z2+e2)) — bit-identical to the
// 4x-validated path; packed (distbits<<32|k) min = first-index tie-break.
// MFMA layouts: C/D col=lane&15,row=(lane>>4)*4+reg [m89-verified];
// A: row=lane&15, k=(lane>>4)*8+j; B: col=lane&15, k=(lane>>4)*8+j.
// ---------------------------------------------------------------------------
__global__ __launch_bounds__(256, 2) void k_approx(
        const float* __restrict__ z, const float* __restrict__ e,
        const unsigned short* __restrict__ ehi,
        const unsigned short* __restrict__ elo,
        const float* __restrict__ z2, const float* __restrict__ e2,
        float* __restrict__ outIdx, int* __restrict__ wsIdx) {
    __shared__ int cnt[4][16];
    __shared__ int candK[4][16][CAP];

    const int t    = threadIdx.x;
    const int lane = t & 63;
    const int w    = t >> 6;
    const int col  = lane & 15;   // A-row / B-code / acc-col lane role
    const int kg   = lane >> 4;   // k-group 0..3

    const int n0  = (blockIdx.x * 4 + w) * 16;  // wave's first row
    const int b   = n0 >> 10;
    const int nl0 = n0 & 1023;

    if (t < 64) cnt[t >> 4][t & 15] = 0;
    __syncthreads();

    // ---- A-panel: lane holds row 'col', d = s*32 + kg*8 + j ----
    const float* zp = z + (size_t)b * (D_DIM * 1024) + nl0 + col;
    short8 ah[8], al[8];
#pragma unroll
    for (int s = 0; s < 8; ++s) {
        float f[8];
#pragma unroll
        for (int j = 0; j < 8; ++j)
            f[j] = zp[(size_t)(s * 32 + kg * 8 + j) * 1024];
        Pack8 ph, pl;
#pragma unroll
        for (int p = 0; p < 4; ++p) {
            unsigned int h0 = bfr(f[2 * p]);
            unsigned int h1 = bfr(f[2 * p + 1]);
            unsigned int l0 = bfr(f[2 * p]     - bf2f(h0));
            unsigned int l1 = bfr(f[2 * p + 1] - bf2f(h1));
            ph.u[p] = h0 | (h1 << 16);
            pl.u[p] = l0 | (l1 << 16);
        }
        ah[s] = ph.s8;
        al[s] = pl.s8;
    }

    float m[4] = { 1e30f, 1e30f, 1e30f, 1e30f };

#define SHARE_M()                                                        \
    do {                                                                 \
        _Pragma("unroll")                                                \
        for (int r = 0; r < 4; ++r) {                                    \
            _Pragma("unroll")                                            \
            for (int dlt = 1; dlt < 16; dlt <<= 1)                       \
                m[r] = fminf(m[r], __shfl_xor(m[r], dlt, 64));           \
        }                                                                \
    } while (0)

    for (int ct = 0; ct < 64; ++ct) {
        const unsigned short* bh = ehi + (size_t)(ct * 16 + col) * D_DIM + kg * 8;
        const unsigned short* bl = elo + (size_t)(ct * 16 + col) * D_DIM + kg * 8;
        f32x4 accA = { 0.f, 0.f, 0.f, 0.f };
        f32x4 accB = { 0.f, 0.f, 0.f, 0.f };
#pragma unroll
        for (int s = 0; s < 8; ++s) {
            short8 vh = *(const short8*)(bh + s * 32);
            short8 vl = *(const short8*)(bl + s * 32);
            if (s & 1) {
                accB = __builtin_amdgcn_mfma_f32_16x16x32_bf16(ah[s], vh, accB, 0, 0, 0);
                accB = __builtin_amdgcn_mfma_f32_16x16x32_bf16(al[s], vh, accB, 0, 0, 0);
                accB = __builtin_amdgcn_mfma_f32_16x16x32_bf16(ah[s], vl, accB, 0, 0, 0);
            } else {
                accA = __builtin_amdgcn_mfma_f32_16x16x32_bf16(ah[s], vh, accA, 0, 0, 0);
                accA = __builtin_amdgcn_mfma_f32_16x16x32_bf16(al[s], vh, accA, 0, 0, 0);
                accA = __builtin_amdgcn_mfma_f32_16x16x32_bf16(ah[s], vl, accA, 0, 0, 0);
            }
        }
        float e2k = e2[ct * 16 + col];
        float s4[4];
#pragma unroll
        for (int r = 0; r < 4; ++r) {
            float zev = accA[r] + accB[r];
            s4[r] = fmaf(-2.f, zev, e2k);        // approx score (z2-free)
        }
        if (ct == 0) {                           // seed + share before capture
#pragma unroll
            for (int r = 0; r < 4; ++r) m[r] = s4[r];
            SHARE_M();
        }
#pragma unroll
        for (int r = 0; r < 4; ++r) {
            if (s4[r] <= m[r] + MARGIN) {
                int rl = kg * 4 + r;
                int slot = atomicAdd(&cnt[w][rl], 1);
                if (slot < CAP) candK[w][rl][slot] = ct * 16 + col;
            }
        }
#pragma unroll
        for (int r = 0; r < 4; ++r) m[r] = fminf(m[r], s4[r]);
        if ((ct & 1) && ct < 63) SHARE_M();
    }
#undef SHARE_M

    __syncthreads();

    // ---- exact rescore: lane handles row col, candidate slots kg + 4*i ----
    const int rl = col;
    const int n  = n0 + rl;
    const int cntr = min(cnt[w][rl], CAP);
    const float z2r = z2[n];
    const float* zrow = z + (size_t)b * (D_DIM * 1024) + (n & 1023);
    unsigned long long key = 0xFFFFFFFFFFFFFFFFULL;
    for (int i = 0; i < 8; ++i) {
        int ci = kg + i * 4;
        bool act = ci < cntr;
        if (!__any(act)) break;
        if (act) {
            int k = candK[w][rl][ci];
            unsigned long long kk;
            if (cntr == 1) {
                kk = (unsigned long long)(unsigned int)k;  // sole candidate
            } else {
                const float* er = e + (size_t)k * D_DIM;
                float ze = 0.f;
#pragma unroll 8
                for (int d = 0; d < D_DIM; ++d)
                    ze = fmaf(zrow[(size_t)d * 1024], er[d], ze);
                float t1 = z2r + e2[k];              // fl(z2 + e2)
                float dist = fmaf(-2.f, ze, t1);     // fl(t1 - 2*ze)
                kk = ((unsigned long long)__float_as_uint(dist) << 32) |
                     (unsigned int)k;
            }
            if (kk < key) key = kk;
        }
    }
    { unsigned long long o = __shfl_xor(key, 16, 64); if (o < key) key = o;
      o = __shfl_xor(key, 32, 64);                    if (o < key) key = o; }
    if (kg == 0) {
        int k = (int)(unsigned int)(key & 0xFFFFFFFFULL);
        outIdx[n] = (float)k;
        wsIdx[n]  = k;
    }
}

// ---------------------------------------------------------------------------
// Epilogue: z_q gather + straight-through out + loss partial sums (validated).
// ---------------------------------------------------------------------------
__global__ __launch_bounds__(256) void k_epilogue(const float* __restrict__ z,
                                                  const float* __restrict__ e,
                                                  const int* __restrict__ wsIdx,
                                                  float* __restrict__ outZ,
                                                  float* __restrict__ lossAcc) {
    __shared__ float4 zq4[64][64];
    __shared__ int idxs[64];
    const int t = threadIdx.x;
    const int n0 = blockIdx.x * 64;
    const int b = n0 >> 10, nl0 = n0 & 1023;

    if (t < 64) idxs[t] = wsIdx[n0 + t];
    __syncthreads();

#pragma unroll
    for (int j = 0; j < 16; ++j) {
        int flat = j * 256 + t;
        int i  = flat >> 6;
        int c4 = flat & 63;
        float4 v = *(const float4*)(e + (size_t)idxs[i] * D_DIM + c4 * 4);
        zq4[i][c4 ^ (i & 7)] = v;
    }
    __syncthreads();

    const int i  = t & 63;
    const int dg = t >> 6;
    const float* zp = z    + (size_t)b * (D_DIM * 1024) + nl0 + i;
    float*       op = outZ + (size_t)b * (D_DIM * 1024) + nl0 + i;
    float s = 0.f;
#pragma unroll 4
    for (int c = 0; c < 16; ++c) {
        int c4 = dg * 16 + c;
        float4 q = zq4[i][c4 ^ (i & 7)];
        int d = c4 * 4;
        float zv, df;
        zv = zp[(size_t)(d + 0) * 1024]; df = q.x - zv; s = fmaf(df, df, s); op[(size_t)(d + 0) * 1024] = zv + df;
        zv = zp[(size_t)(d + 1) * 1024]; df = q.y - zv; s = fmaf(df, df, s); op[(size_t)(d + 1) * 1024] = zv + df;
        zv = zp[(size_t)(d + 2) * 1024]; df = q.z - zv; s = fmaf(df, df, s); op[(size_t)(d + 2) * 1024] = zv + df;
        zv = zp[(size_t)(d + 3) * 1024]; df = q.w - zv; s = fmaf(df, df, s); op[(size_t)(d + 3) * 1024] = zv + df;
    }
#pragma unroll
    for (int off = 32; off > 0; off >>= 1) s += __shfl_down(s, off, 64);
    if ((t & 63) == 0) atomicAdd(lossAcc, s);
}

__global__ void k_final(const float* __restrict__ lossAcc,
                        float* __restrict__ outLoss) {
    float m = lossAcc[0] * (1.0f / 8388608.0f);
    outLoss[0] = m + 0.25f * m;
}

// ---------------------------------------------------------------------------
extern "C" void kernel_launch(void* const* d_in, const int* in_sizes, int n_in,
                              void* d_out, int out_size, void* d_ws, size_t ws_size,
                              hipStream_t stream) {
    const float* z = (const float*)d_in[0];   // (32,256,32,32)
    const float* e = (const float*)d_in[1];   // (1024,256)
    float* out     = (float*)d_out;
    float* outIdx  = out + 8388608;
    float* outLoss = out + 8421376;

    float* z2      = (float*)d_ws;                        // 32768 f
    float* e2      = z2 + 32768;                          // 1024 f
    float* lossAcc = e2 + 1024;                           // 1 f
    int*   wsIdx   = (int*)(lossAcc + 1);                 // 32768 i
    unsigned short* ehi = (unsigned short*)(wsIdx + 32768);   // 262144 u16
    unsigned short* elo = ehi + 262144;                       // 262144 u16

    k_prep<<<164, 256, 0, stream>>>(z, e, z2, e2, ehi, elo, lossAcc);
    k_approx<<<512, 256, 0, stream>>>(z, e, ehi, elo, z2, e2, outIdx, wsIdx);
    k_epilogue<<<512, 256, 0, stream>>>(z, e, wsIdx, out, lossAcc);
    k_final<<<1, 1, 0, stream>>>(lossAcc, outLoss);
}